// Round 14
// baseline (8788.680 us; speedup 1.0000x reference)
//
#include <hip/hip_runtime.h>
#include <hip/hip_bf16.h>
#include <math.h>

// v12 — v11 + dwconv fused into pw-GEMM A-staging (FL_DW): A rows are trunk
// rows; dwconv is elementwise-in-c -> 3-tap combine in the xform (MFMA-shadow
// VALU, 70% idle). GN stats via read-only pre-pass (k_dwstats). act buffer
// eliminated for TCN layers; trunk ping-pongs (in-place would race t+-d reads).
// Saves ~109 MB HBM/layer + the dwconv write kernel.
//
// bit_conv1d(x,w,s) == conv(x, sign(w)) * mean|w| * s  (x_scale cancels).

#define EPSF 1e-5f

constexpr int B_   = 16;
constexpr int TIN  = 64000;
constexpr int TOUT = 3201;
constexpr int TPAD = 3328;   // 26*128, 52*64
constexpr int E_   = 512;
constexpr int BNC  = 256;
constexpr int C_   = 512;
constexpr int NT   = 24;
constexpr int H_   = 256;
constexpr int NM   = TPAD / 128;  // 26
constexpr int NM64 = TPAD / 64;   // 52

#define FL_GN    2   // GN affine + PReLU during A staging
#define FL_RES   8   // residual add from Res
#define FL_DW    32  // fused depthwise 3-tap conv in A staging

typedef __attribute__((ext_vector_type(8))) short short8;
typedef __attribute__((ext_vector_type(4))) float floatx4;

__device__ __forceinline__ float b2f(short s) {
    unsigned u = ((unsigned)(unsigned short)s) << 16;
    float f; __builtin_memcpy(&f, &u, 4); return f;
}
__device__ __forceinline__ short f2b(float f) {          // RTE (one-time prep)
    __hip_bfloat16 h = __float2bfloat16(f);
    short s; __builtin_memcpy(&s, &h, 2); return s;
}
__device__ __forceinline__ short f2b_fast(float f) {     // 2-op round-half-up
    unsigned u; __builtin_memcpy(&u, &f, 4);
    return (short)((u + 0x8000u) >> 16);
}
__device__ __forceinline__ short bsign(float w) {
    return (w > 0.f) ? (short)0x3F80 : ((w < 0.f) ? (short)0xBF80 : (short)0);
}
__device__ __forceinline__ float fsign(float w) {
    return (w > 0.f) ? 1.f : ((w < 0.f) ? -1.f : 0.f);
}

__device__ float blockReduceSum(float v, float* red, int nw) {
    __syncthreads();
    int lane = threadIdx.x & 63, wid = threadIdx.x >> 6;
#pragma unroll
    for (int o = 32; o > 0; o >>= 1) v += __shfl_down(v, o, 64);
    if (lane == 0) red[wid] = v;
    __syncthreads();
    if (threadIdx.x == 0) {
        float s = 0.f;
        for (int i = 0; i < nw; ++i) s += red[i];
        red[0] = s;
    }
    __syncthreads();
    return red[0];
}

// --- weight prep -----------------------------------------------------------
__global__ void k_signcvt(const float* __restrict__ src,
                          __hip_bfloat16* __restrict__ dst, int n) {
    int i = (blockIdx.x * 256 + threadIdx.x) * 8;
    if (i >= n) return;
    float4 a = *(const float4*)(src + i);
    float4 c = *(const float4*)(src + i + 4);
    short8 v;
    v[0]=bsign(a.x); v[1]=bsign(a.y); v[2]=bsign(a.z); v[3]=bsign(a.w);
    v[4]=bsign(c.x); v[5]=bsign(c.y); v[6]=bsign(c.z); v[7]=bsign(c.w);
    *(short8*)(dst + i) = v;
}

__global__ void k_encw(const float* __restrict__ src,
                       __hip_bfloat16* __restrict__ dst) {
    int id = blockIdx.x * 256 + threadIdx.x;   // 4096 threads
    int r = id >> 3, cc = id & 7;
    short8 v = (short8){0,0,0,0,0,0,0,0};
    if (cc < 5) {
        const float* s = src + r * 40 + cc * 8;
#pragma unroll
        for (int e = 0; e < 8; ++e) v[e] = f2b(s[e]);
    }
    *(short8*)(dst + r * 64 + cc * 8) = v;
}

// --- sum|w| ----------------------------------------------------------------
__global__ void k_absmean(const float* __restrict__ p, int n, int slice_stride,
                          float* __restrict__ out) {
    __shared__ float red[8];
    const float* q = p + (size_t)blockIdx.y * (size_t)slice_stride;
    float s = 0.f;
    for (int i = blockIdx.x * blockDim.x + threadIdx.x; i < n;
         i += gridDim.x * blockDim.x)
        s += fabsf(q[i]);
    s = blockReduceSum(s, red, 4);
    if (threadIdx.x == 0) atomicAdd(out + blockIdx.y, s);
}

// --- templated pipelined MFMA GEMM (256 thr): 64m x 256n, 4 waves of 64x64 -
// Y[b,t,n] = alpha * sum_k A'[b,t,k] * Bw[n,k]
// FL_DW: A'[t][k] = GnPrelu( w0[k]*A[t-d][k] + w1[k]*A[t][k] + w2[k]*A[t+d][k] )
template <int FLAGS>
__global__ __launch_bounds__(256, 3) void k_gemm(
    const __hip_bfloat16* __restrict__ Aact,
    const __hip_bfloat16* __restrict__ Bw, __hip_bfloat16* __restrict__ Yout,
    const __hip_bfloat16* __restrict__ Res,
    const float* __restrict__ gnstats, const float* __restrict__ gamma,
    const float* __restrict__ beta, const float* __restrict__ prelu, float invN,
    const float* __restrict__ dwW, int d,
    const float* __restrict__ wsum, float inv_nw, const float* __restrict__ scale,
    int K, int N, int nnshift) {
    __shared__ __align__(16) short As[64 * 64];    // 8 KB
    __shared__ __align__(16) short Bs[256 * 64];   // 32 KB

    int tid = threadIdx.x;
    int gid = blockIdx.x;
    int xcd = gid & 7, grp = gid >> 3;
    int nidx = grp & ((1 << nnshift) - 1);
    int mb = (grp >> nnshift) * 8 + xcd;
    int m0 = (mb % NM64) * 64;
    int b  = mb / NM64;
    int n0 = nidx * 256;

    int lane = tid & 63, wn = tid >> 6;
    int l15 = lane & 15, quad = lane >> 4;

    float mean = 0.f, ginv = 1.f, pr = 0.f;
    if (FLAGS & FL_GN) {
        float s0 = gnstats[b * 2], s1 = gnstats[b * 2 + 1];
        mean = s0 * invN;
        float var  = s1 * invN - mean * mean;
        ginv = rsqrtf(var + EPSF);
        pr = prelu[0];
    }

    floatx4 acc[4][4];
#pragma unroll
    for (int i = 0; i < 4; ++i)
#pragma unroll
        for (int j = 0; j < 4; ++j) acc[i][j] = (floatx4){0.f, 0.f, 0.f, 0.f};

    constexpr int NRA = (FLAGS & FL_DW) ? 6 : 2;
    short8 ra[NRA], rb[8];
    int r0 = tid >> 3, cc = tid & 7;
    int nk = K >> 6;

    auto loadRaw = [&](int kt) {
        int k0 = kt * 64;
        if (FLAGS & FL_DW) {
#pragma unroll
            for (int j = 0; j < 2; ++j) {
                int t = m0 + j * 32 + r0;
                const __hip_bfloat16* rm = Aact +
                    ((size_t)b * TPAD + t) * K + k0 + cc * 8;
                ra[j * 3 + 1] = *(const short8*)rm;
                ra[j * 3 + 0] = (t >= d)
                    ? *(const short8*)(rm - (size_t)d * K)
                    : (short8){0,0,0,0,0,0,0,0};
                ra[j * 3 + 2] = (t + d < TPAD)
                    ? *(const short8*)(rm + (size_t)d * K)
                    : (short8){0,0,0,0,0,0,0,0};
            }
        } else {
#pragma unroll
            for (int j = 0; j < 2; ++j)
                ra[j] = *(const short8*)(Aact +
                    ((size_t)b * TPAD + m0 + j * 32 + r0) * K + k0 + cc * 8);
        }
#pragma unroll
        for (int j = 0; j < 8; ++j)
            rb[j] = *(const short8*)(Bw + (size_t)(n0 + j * 32 + r0) * K
                                     + k0 + cc * 8);
    };

    auto xform = [&](int kt) {
        if (!(FLAGS & FL_GN)) return;
        int k = kt * 64 + cc * 8;
        float4 g0 = *(const float4*)(gamma + k);
        float4 g1 = *(const float4*)(gamma + k + 4);
        float4 b0 = *(const float4*)(beta + k);
        float4 b1 = *(const float4*)(beta + k + 4);
        float gs[8] = {g0.x,g0.y,g0.z,g0.w,g1.x,g1.y,g1.z,g1.w};
        float bs[8] = {b0.x,b0.y,b0.z,b0.w,b1.x,b1.y,b1.z,b1.w};
        float sc[8], sh[8];
#pragma unroll
        for (int e = 0; e < 8; ++e) {
            sc[e] = gs[e] * ginv;
            sh[e] = bs[e] - mean * sc[e];
        }
        float wv[24];
        if (FLAGS & FL_DW) {
            const float* wp = dwW + (size_t)k * 3;   // 24 contiguous floats
#pragma unroll
            for (int q = 0; q < 6; ++q) ((float4*)wv)[q] = *(const float4*)(wp + q * 4);
        }
#pragma unroll
        for (int j = 0; j < 2; ++j) {
            if (m0 + j * 32 + r0 < TOUT) {
                short8 v;
                if (FLAGS & FL_DW) {
                    short8 p = ra[j * 3 + 0], m = ra[j * 3 + 1], nx = ra[j * 3 + 2];
#pragma unroll
                    for (int e = 0; e < 8; ++e) {
                        float f = wv[e * 3 + 1] * b2f(m[e])
                                + wv[e * 3 + 0] * b2f(p[e])
                                + wv[e * 3 + 2] * b2f(nx[e]);
                        f = f * sc[e] + sh[e];
                        f = fmaxf(f, 0.f) + pr * fminf(f, 0.f);
                        v[e] = f2b_fast(f);
                    }
                } else {
                    v = ra[j];
#pragma unroll
                    for (int e = 0; e < 8; ++e) {
                        float f = b2f(v[e]) * sc[e] + sh[e];
                        f = fmaxf(f, 0.f) + pr * fminf(f, 0.f);
                        v[e] = f2b_fast(f);
                    }
                }
                ra[j * (NRA / 2)] = v;   // result slot: j*3 (DW) or j (plain)
            } else {
                ra[j * (NRA / 2)] = (short8){0,0,0,0,0,0,0,0};
            }
        }
    };

    int sw = (cc ^ (r0 & 7)) * 8;
    loadRaw(0);
    xform(0);
    for (int kt = 0; kt < nk; ++kt) {
        __syncthreads();
#pragma unroll
        for (int j = 0; j < 2; ++j)
            *(short8*)&As[(j * 32 + r0) * 64 + sw] = ra[j * (NRA / 2)];
#pragma unroll
        for (int j = 0; j < 8; ++j)
            *(short8*)&Bs[(j * 32 + r0) * 64 + sw] = rb[j];
        __syncthreads();
        if (kt + 1 < nk) loadRaw(kt + 1);
#pragma unroll
        for (int s = 0; s < 2; ++s) {
            short8 af[4], bf[4];
#pragma unroll
            for (int i = 0; i < 4; ++i) {
                int row = i * 16 + l15;
                int ch = (s * 4 + quad) ^ (row & 7);
                af[i] = *(const short8*)&As[row * 64 + ch * 8];
            }
#pragma unroll
            for (int j = 0; j < 4; ++j) {
                int row = wn * 64 + j * 16 + l15;
                int ch = (s * 4 + quad) ^ (row & 7);
                bf[j] = *(const short8*)&Bs[row * 64 + ch * 8];
            }
#pragma unroll
            for (int i = 0; i < 4; ++i)
#pragma unroll
                for (int j = 0; j < 4; ++j)
                    acc[i][j] = __builtin_amdgcn_mfma_f32_16x16x32_bf16(
                        af[i], bf[j], acc[i][j], 0, 0, 0);
        }
        if (kt + 1 < nk) xform(kt + 1);
    }

    float alpha = wsum[0] * inv_nw * scale[0];
#pragma unroll
    for (int i = 0; i < 4; ++i) {
#pragma unroll
        for (int j = 0; j < 4; ++j) {
            int tb = m0 + i * 16 + quad * 4;
            int n  = n0 + wn * 64 + j * 16 + l15;
#pragma unroll
            for (int r = 0; r < 4; ++r) {
                int t = tb + r;
                float v = alpha * acc[i][j][r];
                size_t off = ((size_t)b * TPAD + t) * N + n;
                if (FLAGS & FL_RES) v += b2f(*(const short*)(Res + off));
                *(short*)(Yout + off) = f2b_fast(v);
            }
        }
    }
}

// --- encoder GEMM (separate: x-window A staging; one K-tile) ---------------
__global__ __launch_bounds__(512) void k_gemm_enc(
    const float* __restrict__ xraw, const __hip_bfloat16* __restrict__ Bw,
    __hip_bfloat16* __restrict__ Yout, float* __restrict__ statsOut) {
    __shared__ __align__(16) short As[128 * 64];
    __shared__ __align__(16) short Bs[256 * 64];
    __shared__ float red[8];

    int tid = threadIdx.x;
    int gid = blockIdx.x;
    int xcd = gid & 7, grp = gid >> 3;
    int nidx = grp & 1;
    int mb = (grp >> 1) * 8 + xcd;
    int m0 = (mb % NM) * 128;
    int b  = mb / NM;
    int n0 = nidx * 256;

    int lane = tid & 63, wid = tid >> 6;
    int wm = wid >> 2, wn = wid & 3;
    int l15 = lane & 15, quad = lane >> 4;

    floatx4 acc[4][4];
#pragma unroll
    for (int i = 0; i < 4; ++i)
#pragma unroll
        for (int j = 0; j < 4; ++j) acc[i][j] = (floatx4){0.f, 0.f, 0.f, 0.f};

    int r0 = tid >> 3, cc = tid & 7;
    int sw = (cc ^ (r0 & 7)) * 8;
    const float* xp = xraw + (size_t)b * TIN;

#pragma unroll
    for (int j = 0; j < 2; ++j) {
        int t = m0 + j * 64 + r0;
        short8 v = (short8){0,0,0,0,0,0,0,0};
        if (t < TOUT && cc < 5) {
            int base = 20 * t + cc * 8 - 20;
            if (base >= 0 && base + 8 <= TIN) {
                float4 x0 = *(const float4*)(xp + base);
                float4 x1 = *(const float4*)(xp + base + 4);
                v[0]=f2b(x0.x); v[1]=f2b(x0.y); v[2]=f2b(x0.z); v[3]=f2b(x0.w);
                v[4]=f2b(x1.x); v[5]=f2b(x1.y); v[6]=f2b(x1.z); v[7]=f2b(x1.w);
            } else {
#pragma unroll
                for (int e = 0; e < 8; ++e) {
                    int xi = base + e;
                    if (xi >= 0 && xi < TIN) v[e] = f2b(xp[xi]);
                }
            }
        }
        *(short8*)&As[(j * 64 + r0) * 64 + sw] = v;
    }
#pragma unroll
    for (int j = 0; j < 4; ++j)
        *(short8*)&Bs[(j * 64 + r0) * 64 + sw] =
            *(const short8*)(Bw + (size_t)(n0 + j * 64 + r0) * 64 + cc * 8);
    __syncthreads();
#pragma unroll
    for (int s = 0; s < 2; ++s) {
        short8 af[4], bf[4];
#pragma unroll
        for (int i = 0; i < 4; ++i) {
            int row = wm * 64 + i * 16 + l15;
            int ch = (s * 4 + quad) ^ (row & 7);
            af[i] = *(const short8*)&As[row * 64 + ch * 8];
        }
#pragma unroll
        for (int j = 0; j < 4; ++j) {
            int row = wn * 64 + j * 16 + l15;
            int ch = (s * 4 + quad) ^ (row & 7);
            bf[j] = *(const short8*)&Bs[row * 64 + ch * 8];
        }
#pragma unroll
        for (int i = 0; i < 4; ++i)
#pragma unroll
            for (int j = 0; j < 4; ++j)
                acc[i][j] = __builtin_amdgcn_mfma_f32_16x16x32_bf16(
                    af[i], bf[j], acc[i][j], 0, 0, 0);
    }

    float ls = 0.f, lq = 0.f;
#pragma unroll
    for (int i = 0; i < 4; ++i) {
#pragma unroll
        for (int j = 0; j < 4; ++j) {
            int tb = m0 + wm * 64 + i * 16 + quad * 4;
            int n  = n0 + wn * 64 + j * 16 + l15;
#pragma unroll
            for (int r = 0; r < 4; ++r) {
                int t = tb + r;
                float v = acc[i][j][r];
                *(short*)(Yout + ((size_t)b * TPAD + t) * E_ + n) = f2b_fast(v);
                if (t < TOUT) { ls += v; lq += v * v; }
            }
        }
    }
    ls = blockReduceSum(ls, red, 8);
    lq = blockReduceSum(lq, red, 8);
    if (tid == 0) {
        atomicAdd(statsOut + b * 2, ls);
        atomicAdd(statsOut + b * 2 + 1, lq);
    }
}

// --- dwconv GN-stats pre-pass (read-only): sum/sumsq of 3-tap conv ---------
__global__ __launch_bounds__(256) void k_dwstats(
    const __hip_bfloat16* __restrict__ trunk, const float* __restrict__ w,
    float* __restrict__ stats, int d) {
    __shared__ float red[8];
    int b = blockIdx.y, t0 = blockIdx.x * 128;
    int tid = threadIdx.x, lane = tid & 63, wv = tid >> 6;
    int c8 = lane * 8;
    float wr[24];
    const float4* wp4 = (const float4*)(w + c8 * 3);
#pragma unroll
    for (int q = 0; q < 6; ++q) ((float4*)wr)[q] = wp4[q];
    const __hip_bfloat16* base = trunk + (size_t)b * TPAD * C_;
    float ls = 0.f, lq = 0.f;
    for (int it = 0; it < 32; ++it) {
        int t = t0 + it * 4 + wv;
        if (t < TOUT) {
            short8 mid = *(const short8*)(base + (size_t)t * C_ + c8);
            short8 prv = (t >= d) ? *(const short8*)(base + (size_t)(t - d) * C_ + c8)
                                  : (short8){0,0,0,0,0,0,0,0};
            short8 nxt = (t + d < TPAD) ? *(const short8*)(base + (size_t)(t + d) * C_ + c8)
                                        : (short8){0,0,0,0,0,0,0,0};
#pragma unroll
            for (int e = 0; e < 8; ++e) {
                float v = wr[e * 3 + 1] * b2f(mid[e])
                        + wr[e * 3 + 0] * b2f(prv[e])
                        + wr[e * 3 + 2] * b2f(nxt[e]);
                ls += v; lq += v * v;
            }
        }
    }
    ls = blockReduceSum(ls, red, 4);
    lq = blockReduceSum(lq, red, 4);
    if (tid == 0) {
        atomicAdd(stats + b * 2, ls);
        atomicAdd(stats + b * 2 + 1, lq);
    }
}

// --- temporal sum ----------------------------------------------------------
__global__ void k_tmean(const __hip_bfloat16* __restrict__ trunk,
                        float* __restrict__ h0) {
    int b = blockIdx.y, t0 = blockIdx.x * 128;
    int tid = threadIdx.x;
    const __hip_bfloat16* base = trunk + (size_t)b * TPAD * C_;
    float s0 = 0.f, s1 = 0.f;
    for (int it = 0; it < 128; ++it) {
        int t = t0 + it;
        if (t >= TOUT) break;
        s0 += b2f(*(const short*)(base + (size_t)t * C_ + tid));
        s1 += b2f(*(const short*)(base + (size_t)t * C_ + tid + 256));
    }
    atomicAdd(h0 + b * C_ + tid, s0);
    atomicAdd(h0 + b * C_ + tid + 256, s1);
}

// --- head ------------------------------------------------------------------
__global__ void k_head(const float* __restrict__ h0,
                       const float* __restrict__ fc1_w, const float* __restrict__ fc1_b,
                       const float* __restrict__ fc1_scale, const float* __restrict__ head_prelu,
                       const float* __restrict__ fco_w, const float* __restrict__ fco_b,
                       const float* __restrict__ fco_scale,
                       const float* __restrict__ wsums, float* __restrict__ out) {
    __shared__ float sh0[512];
    __shared__ float red[8];
    int b = blockIdx.x, tid = threadIdx.x;
    sh0[tid]       = h0[b * C_ + tid] / (float)TOUT;
    sh0[tid + 256] = h0[b * C_ + 256 + tid] / (float)TOUT;
    __syncthreads();
    float av = fabsf(sh0[tid]) + fabsf(sh0[tid + 256]);
    float xs1 = blockReduceSum(av, red, 4) / 512.f;
    xs1 = fmaxf(xs1, EPSF);
    float ws1 = wsums[26] / 131072.f;
    float sc1 = fc1_scale[0];
    const float* wrow = fc1_w + tid * 512;
    float s = 0.f;
    for (int c = 0; c < 512; ++c) s += sh0[c] * fsign(wrow[c]);
    float h1 = s * ws1 * sc1 + fc1_b[tid] * ws1 * xs1 * sc1;
    float a = head_prelu[0];
    h1 = (h1 >= 0.f) ? h1 : a * h1;
    float xs2 = blockReduceSum(fabsf(h1), red, 4) / 256.f;
    xs2 = fmaxf(xs2, EPSF);
    float zpart = h1 * fsign(fco_w[tid]);
    float z = blockReduceSum(zpart, red, 4);
    if (tid == 0) {
        float ws2 = wsums[27] / 256.f;
        float sc2 = fco_scale[0];
        z = z * ws2 * sc2 + fco_b[0] * ws2 * xs2 * sc2;
        out[b] = 1.f / (1.f + expf(-z));
    }
}

extern "C" void kernel_launch(void* const* d_in, const int* in_sizes, int n_in,
                              void* d_out, int out_size, void* d_ws, size_t ws_size,
                              hipStream_t stream) {
    const float* x        = (const float*)d_in[0];
    const float* enc_w    = (const float*)d_in[1];
    const float* enc_g    = (const float*)d_in[2];
    const float* enc_be   = (const float*)d_in[3];
    const float* enc_pr   = (const float*)d_in[4];
    const float* bn_w     = (const float*)d_in[5];
    const float* bn_scale = (const float*)d_in[6];
    const float* ti_w     = (const float*)d_in[7];
    const float* ti_scale = (const float*)d_in[8];
    const float* dw_w     = (const float*)d_in[9];
    const float* pw_w     = (const float*)d_in[10];
    const float* pw_scale = (const float*)d_in[11];
    const float* tg       = (const float*)d_in[12];
    const float* tb       = (const float*)d_in[13];
    const float* tp       = (const float*)d_in[14];
    const float* fc1_w    = (const float*)d_in[15];
    const float* fc1_b    = (const float*)d_in[16];
    const float* fc1_s    = (const float*)d_in[17];
    const float* head_pr  = (const float*)d_in[18];
    const float* fco_w    = (const float*)d_in[19];
    const float* fco_b    = (const float*)d_in[20];
    const float* fco_s    = (const float*)d_in[21];
    float* out = (float*)d_out;

    char* ws = (char*)d_ws;
    size_t fmapH = (size_t)B_ * TPAD * C_ * sizeof(__hip_bfloat16); // 54,525,952
    __hip_bfloat16* trunk0 = (__hip_bfloat16*)ws;
    __hip_bfloat16* act    = (__hip_bfloat16*)(ws + fmapH);
    __hip_bfloat16* trunk1 = (__hip_bfloat16*)(ws + 2 * fmapH);  // was xe
    __hip_bfloat16* xe     = trunk1;                             // enc out (pre-TCN)
    __hip_bfloat16* wenc  = (__hip_bfloat16*)(ws + 3 * fmapH);
    __hip_bfloat16* wbn   = wenc + 512 * 64;
    __hip_bfloat16* wti   = wbn + 256 * 512;
    __hip_bfloat16* wpw   = wti + 512 * 256;
    float* stats = (float*)(wpw + (size_t)NT * 512 * 512);
    float* wsums = stats + 800;
    float* h0    = stats + 832;

    hipMemsetAsync(stats, 0, (832 + B_ * C_) * sizeof(float), stream);

    // weight prep
    k_encw<<<16, 256, 0, stream>>>(enc_w, wenc);
    k_signcvt<<<(256 * 512) / 2048, 256, 0, stream>>>(bn_w, wbn, 256 * 512);
    k_signcvt<<<(512 * 256) / 2048, 256, 0, stream>>>(ti_w, wti, 512 * 256);
    k_signcvt<<<(NT * 512 * 512) / 2048, 256, 0, stream>>>(pw_w, wpw, NT * 512 * 512);

    k_absmean<<<dim3(8, 1),  256, 0, stream>>>(bn_w,  BNC * C_, 0,        wsums + 0);
    k_absmean<<<dim3(8, 1),  256, 0, stream>>>(ti_w,  C_ * BNC, 0,        wsums + 1);
    k_absmean<<<dim3(8, NT), 256, 0, stream>>>(pw_w,  C_ * C_,  C_ * C_,  wsums + 2);
    k_absmean<<<dim3(8, 1),  256, 0, stream>>>(fc1_w, H_ * C_,  0,        wsums + 26);
    k_absmean<<<dim3(1, 1),  256, 0, stream>>>(fco_w, H_,       0,        wsums + 27);

    float invGN = 1.f / ((float)C_ * TOUT);   // E_ == C_ == 512

    // encoder: x windows (K=40 pad 64) x enc_w -> xe(=trunk1) [t][512] + stats 0
    k_gemm_enc<<<NM * B_ * 2, 512, 0, stream>>>(x, wenc, xe, stats);

    // bottleneck: GN(enc)+PReLU fused; xe -> act [t][256]
    k_gemm<FL_GN><<<NM64 * B_, 256, 0, stream>>>(
        xe, wbn, act, nullptr,
        stats, enc_g, enc_be, enc_pr, invGN,
        nullptr, 0,
        wsums + 0, 1.f / (BNC * C_), bn_scale,
        E_, BNC, 0);

    // tcn_input: act -> trunk0 [t][512]
    k_gemm<0><<<NM64 * B_ * 2, 256, 0, stream>>>(
        act, wti, trunk0, nullptr,
        nullptr, nullptr, nullptr, nullptr, 0.f,
        nullptr, 0,
        wsums + 1, 1.f / (C_ * BNC), ti_scale,
        BNC, C_, 1);

    __hip_bfloat16* ping[2] = {trunk0, trunk1};
    for (int i = 0; i < NT; ++i) {
        int d = 1 << (i & 7);
        float* st = stats + (1 + i) * 32;
        __hip_bfloat16* tin  = ping[i & 1];
        __hip_bfloat16* tout = ping[(i + 1) & 1];
        k_dwstats<<<dim3(NM, B_), 256, 0, stream>>>(
            tin, dw_w + (size_t)i * C_ * 3, st, d);
        k_gemm<FL_DW | FL_GN | FL_RES><<<NM64 * B_ * 2, 256, 0, stream>>>(
            tin, wpw + (size_t)i * C_ * C_, tout, tin,
            st, tg + i * C_, tb + i * C_, tp + i, invGN,
            dw_w + (size_t)i * C_ * 3, d,
            wsums + 2 + i, 1.f / (C_ * C_), pw_scale + i,
            C_, C_, 1);
    }

    k_tmean<<<dim3(NM, B_), 256, 0, stream>>>(ping[0], h0);   // NT even -> trunk0
    k_head<<<B_, 256, 0, stream>>>(h0, fc1_w, fc1_b, fc1_s, head_pr,
                                   fco_w, fco_b, fco_s, wsums, out);
}

// Round 15
// 2511.882 us; speedup vs baseline: 3.4988x; 3.4988x over previous
//
#include <hip/hip_runtime.h>
#include <hip/hip_bf16.h>
#include <math.h>

// v13 — v11 (2.67ms champion) + next occupancy rung: wave tile 64x32
// (acc 4x2 = 32 AGPR), block 4 waves = 64m x 128n, rb 8->4.
// Est. ~100-110 total regs; __launch_bounds__(256,4) caps 128 (slack ~20)
// -> 4 waves/SIMD = 16 waves/CU (+33% vs v11). LDS 24KB.
// v12's FL_DW fusion REVERTED (ra[6] blew the reg cap -> 842MB scratch spill).
//
// bit_conv1d(x,w,s) == conv(x, sign(w)) * mean|w| * s  (x_scale cancels).

#define EPSF 1e-5f

constexpr int B_   = 16;
constexpr int TIN  = 64000;
constexpr int TOUT = 3201;
constexpr int TPAD = 3328;   // 26*128, 52*64
constexpr int E_   = 512;
constexpr int BNC  = 256;
constexpr int C_   = 512;
constexpr int NT   = 24;
constexpr int H_   = 256;
constexpr int NM   = TPAD / 128;  // 26
constexpr int NM64 = TPAD / 64;   // 52

#define FL_GN    2   // GN affine + PReLU during A staging
#define FL_RES   8   // residual add from Res

typedef __attribute__((ext_vector_type(8))) short short8;
typedef __attribute__((ext_vector_type(4))) float floatx4;

__device__ __forceinline__ float b2f(short s) {
    unsigned u = ((unsigned)(unsigned short)s) << 16;
    float f; __builtin_memcpy(&f, &u, 4); return f;
}
__device__ __forceinline__ short f2b(float f) {          // RTE (one-time prep)
    __hip_bfloat16 h = __float2bfloat16(f);
    short s; __builtin_memcpy(&s, &h, 2); return s;
}
__device__ __forceinline__ short f2b_fast(float f) {     // 2-op round-half-up
    unsigned u; __builtin_memcpy(&u, &f, 4);
    return (short)((u + 0x8000u) >> 16);
}
__device__ __forceinline__ short bsign(float w) {
    return (w > 0.f) ? (short)0x3F80 : ((w < 0.f) ? (short)0xBF80 : (short)0);
}
__device__ __forceinline__ float fsign(float w) {
    return (w > 0.f) ? 1.f : ((w < 0.f) ? -1.f : 0.f);
}

__device__ float blockReduceSum(float v, float* red, int nw) {
    __syncthreads();
    int lane = threadIdx.x & 63, wid = threadIdx.x >> 6;
#pragma unroll
    for (int o = 32; o > 0; o >>= 1) v += __shfl_down(v, o, 64);
    if (lane == 0) red[wid] = v;
    __syncthreads();
    if (threadIdx.x == 0) {
        float s = 0.f;
        for (int i = 0; i < nw; ++i) s += red[i];
        red[0] = s;
    }
    __syncthreads();
    return red[0];
}

// --- weight prep -----------------------------------------------------------
__global__ void k_signcvt(const float* __restrict__ src,
                          __hip_bfloat16* __restrict__ dst, int n) {
    int i = (blockIdx.x * 256 + threadIdx.x) * 8;
    if (i >= n) return;
    float4 a = *(const float4*)(src + i);
    float4 c = *(const float4*)(src + i + 4);
    short8 v;
    v[0]=bsign(a.x); v[1]=bsign(a.y); v[2]=bsign(a.z); v[3]=bsign(a.w);
    v[4]=bsign(c.x); v[5]=bsign(c.y); v[6]=bsign(c.z); v[7]=bsign(c.w);
    *(short8*)(dst + i) = v;
}

__global__ void k_encw(const float* __restrict__ src,
                       __hip_bfloat16* __restrict__ dst) {
    int id = blockIdx.x * 256 + threadIdx.x;   // 4096 threads
    int r = id >> 3, cc = id & 7;
    short8 v = (short8){0,0,0,0,0,0,0,0};
    if (cc < 5) {
        const float* s = src + r * 40 + cc * 8;
#pragma unroll
        for (int e = 0; e < 8; ++e) v[e] = f2b(s[e]);
    }
    *(short8*)(dst + r * 64 + cc * 8) = v;
}

// --- sum|w| ----------------------------------------------------------------
__global__ void k_absmean(const float* __restrict__ p, int n, int slice_stride,
                          float* __restrict__ out) {
    __shared__ float red[8];
    const float* q = p + (size_t)blockIdx.y * (size_t)slice_stride;
    float s = 0.f;
    for (int i = blockIdx.x * blockDim.x + threadIdx.x; i < n;
         i += gridDim.x * blockDim.x)
        s += fabsf(q[i]);
    s = blockReduceSum(s, red, 4);
    if (threadIdx.x == 0) atomicAdd(out + blockIdx.y, s);
}

// --- templated pipelined MFMA GEMM (256 thr): 64m x 128n, 4 waves of 64x32 -
// Y[b,t,n] = alpha * sum_k A'[b,t,k] * Bw[n,k]
template <int FLAGS>
__global__ __launch_bounds__(256, 4) void k_gemm(
    const __hip_bfloat16* __restrict__ Aact,
    const __hip_bfloat16* __restrict__ Bw, __hip_bfloat16* __restrict__ Yout,
    const __hip_bfloat16* __restrict__ Res,
    const float* __restrict__ gnstats, const float* __restrict__ gamma,
    const float* __restrict__ beta, const float* __restrict__ prelu, float invN,
    const float* __restrict__ wsum, float inv_nw, const float* __restrict__ scale,
    int K, int N, int nnshift) {
    __shared__ __align__(16) short As[64 * 64];    // 8 KB
    __shared__ __align__(16) short Bs[128 * 64];   // 16 KB

    int tid = threadIdx.x;
    int gid = blockIdx.x;
    int xcd = gid & 7, grp = gid >> 3;
    int nidx = grp & ((1 << nnshift) - 1);
    int mb = (grp >> nnshift) * 8 + xcd;
    int m0 = (mb % NM64) * 64;
    int b  = mb / NM64;
    int n0 = nidx * 128;

    int lane = tid & 63, wn = tid >> 6;   // wave n-index 0..3 (32n each)
    int l15 = lane & 15, quad = lane >> 4;

    float mean = 0.f, ginv = 1.f, pr = 0.f;
    if (FLAGS & FL_GN) {
        float s0 = gnstats[b * 2], s1 = gnstats[b * 2 + 1];
        mean = s0 * invN;
        float var  = s1 * invN - mean * mean;
        ginv = rsqrtf(var + EPSF);
        pr = prelu[0];
    }

    floatx4 acc[4][2];
#pragma unroll
    for (int i = 0; i < 4; ++i)
#pragma unroll
        for (int j = 0; j < 2; ++j) acc[i][j] = (floatx4){0.f, 0.f, 0.f, 0.f};

    short8 ra[2], rb[4];
    int r0 = tid >> 3, cc = tid & 7;   // A rows r0, r0+32 ; B rows r0+32j
    int nk = K >> 6;

    auto loadRaw = [&](int kt) {
        int k0 = kt * 64;
#pragma unroll
        for (int j = 0; j < 2; ++j)
            ra[j] = *(const short8*)(Aact +
                ((size_t)b * TPAD + m0 + j * 32 + r0) * K + k0 + cc * 8);
#pragma unroll
        for (int j = 0; j < 4; ++j)
            rb[j] = *(const short8*)(Bw + (size_t)(n0 + j * 32 + r0) * K
                                     + k0 + cc * 8);
    };

    auto xform = [&](int kt) {
        if (!(FLAGS & FL_GN)) return;
        int k = kt * 64 + cc * 8;
        float4 g0 = *(const float4*)(gamma + k);
        float4 g1 = *(const float4*)(gamma + k + 4);
        float4 b0 = *(const float4*)(beta + k);
        float4 b1 = *(const float4*)(beta + k + 4);
        float gs[8] = {g0.x,g0.y,g0.z,g0.w,g1.x,g1.y,g1.z,g1.w};
        float bs[8] = {b0.x,b0.y,b0.z,b0.w,b1.x,b1.y,b1.z,b1.w};
        float sc[8], sh[8];
#pragma unroll
        for (int e = 0; e < 8; ++e) {
            sc[e] = gs[e] * ginv;
            sh[e] = bs[e] - mean * sc[e];
        }
#pragma unroll
        for (int j = 0; j < 2; ++j) {
            if (m0 + j * 32 + r0 < TOUT) {
                short8 v = ra[j];
#pragma unroll
                for (int e = 0; e < 8; ++e) {
                    float f = b2f(v[e]) * sc[e] + sh[e];
                    f = fmaxf(f, 0.f) + pr * fminf(f, 0.f);
                    v[e] = f2b_fast(f);
                }
                ra[j] = v;
            } else {
                ra[j] = (short8){0,0,0,0,0,0,0,0};
            }
        }
    };

    int sw = (cc ^ (r0 & 7)) * 8;
    loadRaw(0);
    xform(0);
    for (int kt = 0; kt < nk; ++kt) {
        __syncthreads();
#pragma unroll
        for (int j = 0; j < 2; ++j)
            *(short8*)&As[(j * 32 + r0) * 64 + sw] = ra[j];
#pragma unroll
        for (int j = 0; j < 4; ++j)
            *(short8*)&Bs[(j * 32 + r0) * 64 + sw] = rb[j];
        __syncthreads();
        if (kt + 1 < nk) loadRaw(kt + 1);
#pragma unroll
        for (int s = 0; s < 2; ++s) {
            short8 af[4], bf[2];
#pragma unroll
            for (int i = 0; i < 4; ++i) {
                int row = i * 16 + l15;
                int ch = (s * 4 + quad) ^ (row & 7);
                af[i] = *(const short8*)&As[row * 64 + ch * 8];
            }
#pragma unroll
            for (int j = 0; j < 2; ++j) {
                int row = wn * 32 + j * 16 + l15;
                int ch = (s * 4 + quad) ^ (row & 7);
                bf[j] = *(const short8*)&Bs[row * 64 + ch * 8];
            }
#pragma unroll
            for (int i = 0; i < 4; ++i)
#pragma unroll
                for (int j = 0; j < 2; ++j)
                    acc[i][j] = __builtin_amdgcn_mfma_f32_16x16x32_bf16(
                        af[i], bf[j], acc[i][j], 0, 0, 0);
        }
        if (kt + 1 < nk) xform(kt + 1);
    }

    float alpha = wsum[0] * inv_nw * scale[0];
#pragma unroll
    for (int i = 0; i < 4; ++i) {
#pragma unroll
        for (int j = 0; j < 2; ++j) {
            int tb = m0 + i * 16 + quad * 4;
            int n  = n0 + wn * 32 + j * 16 + l15;
#pragma unroll
            for (int r = 0; r < 4; ++r) {
                int t = tb + r;
                float v = alpha * acc[i][j][r];
                size_t off = ((size_t)b * TPAD + t) * N + n;
                if (FLAGS & FL_RES) v += b2f(*(const short*)(Res + off));
                *(short*)(Yout + off) = f2b_fast(v);
            }
        }
    }
}

// --- encoder GEMM (separate: x-window A staging; one K-tile) ---------------
__global__ __launch_bounds__(512) void k_gemm_enc(
    const float* __restrict__ xraw, const __hip_bfloat16* __restrict__ Bw,
    __hip_bfloat16* __restrict__ Yout, float* __restrict__ statsOut) {
    __shared__ __align__(16) short As[128 * 64];
    __shared__ __align__(16) short Bs[256 * 64];
    __shared__ float red[8];

    int tid = threadIdx.x;
    int gid = blockIdx.x;
    int xcd = gid & 7, grp = gid >> 3;
    int nidx = grp & 1;
    int mb = (grp >> 1) * 8 + xcd;
    int m0 = (mb % NM) * 128;
    int b  = mb / NM;
    int n0 = nidx * 256;

    int lane = tid & 63, wid = tid >> 6;
    int wm = wid >> 2, wn = wid & 3;
    int l15 = lane & 15, quad = lane >> 4;

    floatx4 acc[4][4];
#pragma unroll
    for (int i = 0; i < 4; ++i)
#pragma unroll
        for (int j = 0; j < 4; ++j) acc[i][j] = (floatx4){0.f, 0.f, 0.f, 0.f};

    int r0 = tid >> 3, cc = tid & 7;
    int sw = (cc ^ (r0 & 7)) * 8;
    const float* xp = xraw + (size_t)b * TIN;

#pragma unroll
    for (int j = 0; j < 2; ++j) {
        int t = m0 + j * 64 + r0;
        short8 v = (short8){0,0,0,0,0,0,0,0};
        if (t < TOUT && cc < 5) {
            int base = 20 * t + cc * 8 - 20;
            if (base >= 0 && base + 8 <= TIN) {
                float4 x0 = *(const float4*)(xp + base);
                float4 x1 = *(const float4*)(xp + base + 4);
                v[0]=f2b(x0.x); v[1]=f2b(x0.y); v[2]=f2b(x0.z); v[3]=f2b(x0.w);
                v[4]=f2b(x1.x); v[5]=f2b(x1.y); v[6]=f2b(x1.z); v[7]=f2b(x1.w);
            } else {
#pragma unroll
                for (int e = 0; e < 8; ++e) {
                    int xi = base + e;
                    if (xi >= 0 && xi < TIN) v[e] = f2b(xp[xi]);
                }
            }
        }
        *(short8*)&As[(j * 64 + r0) * 64 + sw] = v;
    }
#pragma unroll
    for (int j = 0; j < 4; ++j)
        *(short8*)&Bs[(j * 64 + r0) * 64 + sw] =
            *(const short8*)(Bw + (size_t)(n0 + j * 64 + r0) * 64 + cc * 8);
    __syncthreads();
#pragma unroll
    for (int s = 0; s < 2; ++s) {
        short8 af[4], bf[4];
#pragma unroll
        for (int i = 0; i < 4; ++i) {
            int row = wm * 64 + i * 16 + l15;
            int ch = (s * 4 + quad) ^ (row & 7);
            af[i] = *(const short8*)&As[row * 64 + ch * 8];
        }
#pragma unroll
        for (int j = 0; j < 4; ++j) {
            int row = wn * 64 + j * 16 + l15;
            int ch = (s * 4 + quad) ^ (row & 7);
            bf[j] = *(const short8*)&Bs[row * 64 + ch * 8];
        }
#pragma unroll
        for (int i = 0; i < 4; ++i)
#pragma unroll
            for (int j = 0; j < 4; ++j)
                acc[i][j] = __builtin_amdgcn_mfma_f32_16x16x32_bf16(
                    af[i], bf[j], acc[i][j], 0, 0, 0);
    }

    float ls = 0.f, lq = 0.f;
#pragma unroll
    for (int i = 0; i < 4; ++i) {
#pragma unroll
        for (int j = 0; j < 4; ++j) {
            int tb = m0 + wm * 64 + i * 16 + quad * 4;
            int n  = n0 + wn * 64 + j * 16 + l15;
#pragma unroll
            for (int r = 0; r < 4; ++r) {
                int t = tb + r;
                float v = acc[i][j][r];
                *(short*)(Yout + ((size_t)b * TPAD + t) * E_ + n) = f2b_fast(v);
                if (t < TOUT) { ls += v; lq += v * v; }
            }
        }
    }
    ls = blockReduceSum(ls, red, 8);
    lq = blockReduceSum(lq, red, 8);
    if (tid == 0) {
        atomicAdd(statsOut + b * 2, ls);
        atomicAdd(statsOut + b * 2 + 1, lq);
    }
}

// --- depthwise conv k=3 dil d, [t][c] bf16 -> [t][c] bf16 + GN stats -------
__global__ __launch_bounds__(256) void k_dwconv(
    const __hip_bfloat16* __restrict__ trunk, const float* __restrict__ w,
    __hip_bfloat16* __restrict__ act, float* __restrict__ stats, int d) {
    __shared__ float red[8];
    int b = blockIdx.y, t0 = blockIdx.x * 128;
    int tid = threadIdx.x, lane = tid & 63, wv = tid >> 6;
    int c8 = lane * 8;
    float wr[24];
    const float4* wp4 = (const float4*)(w + c8 * 3);
#pragma unroll
    for (int q = 0; q < 6; ++q) ((float4*)wr)[q] = wp4[q];
    const __hip_bfloat16* base = trunk + (size_t)b * TPAD * C_;
    __hip_bfloat16* ob = act + (size_t)b * TPAD * C_;
    float ls = 0.f, lq = 0.f;
    for (int it = 0; it < 32; ++it) {
        int t = t0 + it * 4 + wv;
        if (t < TOUT) {
            short8 mid = *(const short8*)(base + (size_t)t * C_ + c8);
            short8 prv = (t >= d) ? *(const short8*)(base + (size_t)(t - d) * C_ + c8)
                                  : (short8){0,0,0,0,0,0,0,0};
            short8 nxt = (t + d < TPAD) ? *(const short8*)(base + (size_t)(t + d) * C_ + c8)
                                        : (short8){0,0,0,0,0,0,0,0};
            short8 o;
#pragma unroll
            for (int e = 0; e < 8; ++e) {
                float v = wr[e * 3 + 1] * b2f(mid[e])
                        + wr[e * 3 + 0] * b2f(prv[e])
                        + wr[e * 3 + 2] * b2f(nxt[e]);
                o[e] = f2b_fast(v); ls += v; lq += v * v;
            }
            *(short8*)(ob + (size_t)t * C_ + c8) = o;
        } else {
            *(short8*)(ob + (size_t)t * C_ + c8) = (short8){0,0,0,0,0,0,0,0};
        }
    }
    ls = blockReduceSum(ls, red, 4);
    lq = blockReduceSum(lq, red, 4);
    if (tid == 0) {
        atomicAdd(stats + b * 2, ls);
        atomicAdd(stats + b * 2 + 1, lq);
    }
}

// --- temporal sum ----------------------------------------------------------
__global__ void k_tmean(const __hip_bfloat16* __restrict__ trunk,
                        float* __restrict__ h0) {
    int b = blockIdx.y, t0 = blockIdx.x * 128;
    int tid = threadIdx.x;
    const __hip_bfloat16* base = trunk + (size_t)b * TPAD * C_;
    float s0 = 0.f, s1 = 0.f;
    for (int it = 0; it < 128; ++it) {
        int t = t0 + it;
        if (t >= TOUT) break;
        s0 += b2f(*(const short*)(base + (size_t)t * C_ + tid));
        s1 += b2f(*(const short*)(base + (size_t)t * C_ + tid + 256));
    }
    atomicAdd(h0 + b * C_ + tid, s0);
    atomicAdd(h0 + b * C_ + tid + 256, s1);
}

// --- head ------------------------------------------------------------------
__global__ void k_head(const float* __restrict__ h0,
                       const float* __restrict__ fc1_w, const float* __restrict__ fc1_b,
                       const float* __restrict__ fc1_scale, const float* __restrict__ head_prelu,
                       const float* __restrict__ fco_w, const float* __restrict__ fco_b,
                       const float* __restrict__ fco_scale,
                       const float* __restrict__ wsums, float* __restrict__ out) {
    __shared__ float sh0[512];
    __shared__ float red[8];
    int b = blockIdx.x, tid = threadIdx.x;
    sh0[tid]       = h0[b * C_ + tid] / (float)TOUT;
    sh0[tid + 256] = h0[b * C_ + 256 + tid] / (float)TOUT;
    __syncthreads();
    float av = fabsf(sh0[tid]) + fabsf(sh0[tid + 256]);
    float xs1 = blockReduceSum(av, red, 4) / 512.f;
    xs1 = fmaxf(xs1, EPSF);
    float ws1 = wsums[26] / 131072.f;
    float sc1 = fc1_scale[0];
    const float* wrow = fc1_w + tid * 512;
    float s = 0.f;
    for (int c = 0; c < 512; ++c) s += sh0[c] * fsign(wrow[c]);
    float h1 = s * ws1 * sc1 + fc1_b[tid] * ws1 * xs1 * sc1;
    float a = head_prelu[0];
    h1 = (h1 >= 0.f) ? h1 : a * h1;
    float xs2 = blockReduceSum(fabsf(h1), red, 4) / 256.f;
    xs2 = fmaxf(xs2, EPSF);
    float zpart = h1 * fsign(fco_w[tid]);
    float z = blockReduceSum(zpart, red, 4);
    if (tid == 0) {
        float ws2 = wsums[27] / 256.f;
        float sc2 = fco_scale[0];
        z = z * ws2 * sc2 + fco_b[0] * ws2 * xs2 * sc2;
        out[b] = 1.f / (1.f + expf(-z));
    }
}

extern "C" void kernel_launch(void* const* d_in, const int* in_sizes, int n_in,
                              void* d_out, int out_size, void* d_ws, size_t ws_size,
                              hipStream_t stream) {
    const float* x        = (const float*)d_in[0];
    const float* enc_w    = (const float*)d_in[1];
    const float* enc_g    = (const float*)d_in[2];
    const float* enc_be   = (const float*)d_in[3];
    const float* enc_pr   = (const float*)d_in[4];
    const float* bn_w     = (const float*)d_in[5];
    const float* bn_scale = (const float*)d_in[6];
    const float* ti_w     = (const float*)d_in[7];
    const float* ti_scale = (const float*)d_in[8];
    const float* dw_w     = (const float*)d_in[9];
    const float* pw_w     = (const float*)d_in[10];
    const float* pw_scale = (const float*)d_in[11];
    const float* tg       = (const float*)d_in[12];
    const float* tb       = (const float*)d_in[13];
    const float* tp       = (const float*)d_in[14];
    const float* fc1_w    = (const float*)d_in[15];
    const float* fc1_b    = (const float*)d_in[16];
    const float* fc1_s    = (const float*)d_in[17];
    const float* head_pr  = (const float*)d_in[18];
    const float* fco_w    = (const float*)d_in[19];
    const float* fco_b    = (const float*)d_in[20];
    const float* fco_s    = (const float*)d_in[21];
    float* out = (float*)d_out;

    char* ws = (char*)d_ws;
    size_t fmapH = (size_t)B_ * TPAD * C_ * sizeof(__hip_bfloat16); // 54,525,952
    __hip_bfloat16* trunk = (__hip_bfloat16*)ws;
    __hip_bfloat16* act   = (__hip_bfloat16*)(ws + fmapH);
    __hip_bfloat16* xe    = (__hip_bfloat16*)(ws + 2 * fmapH);
    __hip_bfloat16* wenc  = (__hip_bfloat16*)(ws + 3 * fmapH);
    __hip_bfloat16* wbn   = wenc + 512 * 64;
    __hip_bfloat16* wti   = wbn + 256 * 512;
    __hip_bfloat16* wpw   = wti + 512 * 256;
    float* stats = (float*)(wpw + (size_t)NT * 512 * 512);
    float* wsums = stats + 800;
    float* h0    = stats + 832;

    hipMemsetAsync(stats, 0, (832 + B_ * C_) * sizeof(float), stream);

    // weight prep
    k_encw<<<16, 256, 0, stream>>>(enc_w, wenc);
    k_signcvt<<<(256 * 512) / 2048, 256, 0, stream>>>(bn_w, wbn, 256 * 512);
    k_signcvt<<<(512 * 256) / 2048, 256, 0, stream>>>(ti_w, wti, 512 * 256);
    k_signcvt<<<(NT * 512 * 512) / 2048, 256, 0, stream>>>(pw_w, wpw, NT * 512 * 512);

    k_absmean<<<dim3(8, 1),  256, 0, stream>>>(bn_w,  BNC * C_, 0,        wsums + 0);
    k_absmean<<<dim3(8, 1),  256, 0, stream>>>(ti_w,  C_ * BNC, 0,        wsums + 1);
    k_absmean<<<dim3(8, NT), 256, 0, stream>>>(pw_w,  C_ * C_,  C_ * C_,  wsums + 2);
    k_absmean<<<dim3(8, 1),  256, 0, stream>>>(fc1_w, H_ * C_,  0,        wsums + 26);
    k_absmean<<<dim3(1, 1),  256, 0, stream>>>(fco_w, H_,       0,        wsums + 27);

    float invGN = 1.f / ((float)C_ * TOUT);   // E_ == C_ == 512

    // encoder: x windows (K=40 pad 64) x enc_w -> xe [t][512] + stats slot 0
    k_gemm_enc<<<NM * B_ * 2, 512, 0, stream>>>(x, wenc, xe, stats);

    // bottleneck: GN(enc)+PReLU fused; xe -> act [t][256]  (n-split 2)
    k_gemm<FL_GN><<<NM64 * B_ * 2, 256, 0, stream>>>(
        xe, wbn, act, nullptr,
        stats, enc_g, enc_be, enc_pr, invGN,
        wsums + 0, 1.f / (BNC * C_), bn_scale,
        E_, BNC, 1);

    // tcn_input: act -> trunk [t][512]  (n-split 4)
    k_gemm<0><<<NM64 * B_ * 4, 256, 0, stream>>>(
        act, wti, trunk, nullptr,
        nullptr, nullptr, nullptr, nullptr, 0.f,
        wsums + 1, 1.f / (C_ * BNC), ti_scale,
        BNC, C_, 2);

    for (int i = 0; i < NT; ++i) {
        int d = 1 << (i & 7);
        float* st = stats + (1 + i) * 32;
        k_dwconv<<<dim3(NM, B_), 256, 0, stream>>>(
            trunk, dw_w + (size_t)i * C_ * 3, act, st, d);
        k_gemm<FL_GN | FL_RES><<<NM64 * B_ * 4, 256, 0, stream>>>(
            act, wpw + (size_t)i * C_ * C_, trunk, trunk,
            st, tg + i * C_, tb + i * C_, tp + i, invGN,
            wsums + 2 + i, 1.f / (C_ * C_), pw_scale + i,
            C_, C_, 2);
    }

    k_tmean<<<dim3(NM, B_), 256, 0, stream>>>(trunk, h0);
    k_head<<<B_, 256, 0, stream>>>(h0, fc1_w, fc1_b, fc1_s, head_pr,
                                   fco_w, fco_b, fco_s, wsums, out);
}